// Round 3
// baseline (488.722 us; speedup 1.0000x reference)
//
#include <hip/hip_runtime.h>
#include <stdint.h>

// Problem constants (fixed instance)
#define B_    32
#define S_    4096
#define E_    256
#define P_    256
#define M_    16
#define G_    (B_*P_)      // 8192 groups
#define NSLOT (G_*M_)      // 131072 slots (== tokens)
#define ROWS  128          // 8 groups * 16 slots per workgroup
#define NWG   (G_/8)       // 1024 workgroups

typedef float fv4 __attribute__((ext_vector_type(4)));
typedef int   iv4 __attribute__((ext_vector_type(4)));
typedef int   iv2 __attribute__((ext_vector_type(2)));
typedef __bf16 bv8 __attribute__((ext_vector_type(8)));
typedef short  sv4 __attribute__((ext_vector_type(4)));

__device__ __forceinline__ uint32_t bf16rne(float f) {
  uint32_t u = __builtin_bit_cast(uint32_t, f);
  u += 0x7fffu + ((u >> 16) & 1u);
  return u >> 16;
}
__device__ __forceinline__ uint32_t pk2(uint32_t lo, uint32_t hi) {
  return (lo & 0xffffu) | (hi << 16);
}
// Builtins (NOT inline asm): hazard recognizer must see MFMAs (round-1 NaN).
__device__ __forceinline__ void mfma32(fv4& d, iv4 a, iv4 b) {
  d = __builtin_amdgcn_mfma_f32_16x16x32_bf16(
        __builtin_bit_cast(bv8, a), __builtin_bit_cast(bv8, b), d, 0, 0, 0);
}
__device__ __forceinline__ void mfma16(fv4& d, iv2 a, iv2 b) {
  d = __builtin_amdgcn_mfma_f32_16x16x16bf16_1k(
        __builtin_bit_cast(sv4, a), __builtin_bit_cast(sv4, b), d, 0, 0, 0);
}

// XOR swizzle: permutes 16B blocks within 128B sub-rows.
#define SWZ(off, row) ((off) ^ (((row) & 7) << 4))

// ---------------- prep kernels ----------------
__global__ void k_init(int* cnt, int* s2t) {
  int i = blockIdx.x * 256 + threadIdx.x;
  if (i < G_) cnt[i] = 0;
  if (i < NSLOT) s2t[i] = -1;
}

__global__ void k_trans(const float* __restrict__ Wq, const float* __restrict__ Wk,
                        const float* __restrict__ Wv, const float* __restrict__ W0,
                        uint16_t* __restrict__ WT) {
  // WT: 4 concatenated [256][256] bf16, WT[w][n][k] = bf16(W[w][k][n])
  int o = blockIdx.x * 256 + threadIdx.x;     // 0..65535
  int wsel = blockIdx.y;
  const float* W = (wsel == 0) ? Wq : (wsel == 1) ? Wk : (wsel == 2) ? Wv : W0;
  int n = o >> 8, k = o & 255;
  WT[(size_t)wsel * 65536 + o] = (uint16_t)bf16rne(W[k * 256 + n]);
}

__global__ void k_rank(const int* __restrict__ pos, int* cnt, int* s2t) {
  int i = blockIdx.x * 256 + threadIdx.x;
  if (i >= B_ * S_) return;
  int p = pos[i];
  if (p < 0 || p >= P_) return;          // invalid -> dropped (stays -1)
  int b = i >> 12;                       // i / S_
  int g = (b << 8) + p;
  int r = atomicAdd(&cnt[g], 1);         // arbitrary slot order: attention is
  if (r < M_) s2t[g * M_ + r] = i;       // permutation-equivariant, so OK
}

// ---------------- fused main kernel ----------------
// 1 WG = 8 groups = 128 rows, 1024 threads = 16 waves (4 waves/SIMD).
// Wave grid 4x4: wr2 = row-quarter (32 rows), wc4 = col-quarter.
// LDS 128 KiB: [0,64K) X-staging then W tiles; Q/K/V 16K each; ctx 16K.
__global__ __launch_bounds__(1024, 4) void k_main(
    const float* __restrict__ emb, const int* __restrict__ s2t,
    const uint16_t* __restrict__ WT, float* __restrict__ out) {
  extern __shared__ char smem[];
  char* XW = smem;             // 64 KiB
  char* Qb = smem + 65536;     // 16 KiB  [128][64] bf16, 128B rows, swizzled
  char* Kb = smem + 81920;
  char* Vb = smem + 98304;
  char* Cb = smem + 114688;    // ctx

  const uint16_t* WqT = WT;
  const uint16_t* WkT = WT + 65536;
  const uint16_t* WvT = WT + 131072;
  const uint16_t* W0T = WT + 196608;

  const int tid = threadIdx.x;
  const int l = tid & 63;
  const int w = tid >> 6;           // wave 0..15
  const int lane15 = l & 15;
  const int lq = l >> 4;            // lane quad 0..3
  const int wr2 = w >> 2;           // row-quarter 0..3 (32 rows)
  const int wc4 = w & 3;            // col-quarter 0..3
  const int slot0 = blockIdx.x * ROWS;

  // ---- gather: 128 token rows -> bf16 X in LDS (coalesced 1KB row loads) ----
  #pragma unroll
  for (int rl = 0; rl < 8; ++rl) {
    int row = w * 8 + rl;
    int t = s2t[slot0 + row];            // wave-uniform
    uint32_t u0 = 0, u1 = 0;
    if (t >= 0) {
      const float4 v = *reinterpret_cast<const float4*>(emb + (size_t)t * E_ + (l << 2));
      u0 = pk2(bf16rne(v.x), bf16rne(v.y));
      u1 = pk2(bf16rne(v.z), bf16rne(v.w));
    }
    iv2 val; val[0] = (int)u0; val[1] = (int)u1;
    *reinterpret_cast<iv2*>(XW + row * 512 + SWZ(l * 8, row)) = val;
  }
  __syncthreads();

  // ---- X A-fragments into registers: 2 m-tiles x 8 k-steps (64 VGPR) ----
  iv4 xf[2][8];
  #pragma unroll
  for (int mt = 0; mt < 2; ++mt) {
    int row = wr2 * 32 + mt * 16 + lane15;
    #pragma unroll
    for (int ks = 0; ks < 8; ++ks)
      xf[mt][ks] = *reinterpret_cast<const iv4*>(XW + row * 512 + SWZ(ks * 64 + lq * 16, row));
  }
  __syncthreads();   // X region now reusable for weight tiles

  fv4 outacc[2][4];  // 32 rows x 64 cols per wave, persists across chunks
  #pragma unroll
  for (int a = 0; a < 2; ++a)
    #pragma unroll
    for (int b = 0; b < 4; ++b) outacc[a][b] = fv4{0.f, 0.f, 0.f, 0.f};

  for (int hc = 0; hc < 4; ++hc) {       // 4 head-chunks of 64 cols (2 heads)
    const int c0 = hc * 64;

    // ---- stage Wq+Wk chunk tiles (2 x 32KiB) into XW ----
    #pragma unroll
    for (int it = 0; it < 4; ++it) {
      int idx = it * 1024 + tid;         // 0..4095
      int wsel = idx >> 11;              // 0=Wq 1=Wk
      int within = idx & 2047;
      int n = within >> 5, seg = within & 31;
      const uint16_t* Wt = wsel ? WkT : WqT;
      iv4 d = *reinterpret_cast<const iv4*>(
          reinterpret_cast<const char*>(Wt) + (size_t)(c0 + n) * 512 + seg * 16);
      *reinterpret_cast<iv4*>(XW + wsel * 32768 + n * 512 + SWZ(seg * 16, n)) = d;
    }
    __syncthreads();

    // ---- compute Q and K projections ----
    #pragma unroll
    for (int wgt = 0; wgt < 2; ++wgt) {
      char* dstb = wgt ? Kb : Qb;
      const char* wbase = XW + wgt * 32768;
      fv4 acc[2];
      acc[0] = fv4{0.f,0.f,0.f,0.f}; acc[1] = fv4{0.f,0.f,0.f,0.f};
      int n0 = wc4 * 16 + lane15;
      #pragma unroll
      for (int ks = 0; ks < 8; ++ks) {
        iv4 b0 = *reinterpret_cast<const iv4*>(wbase + n0 * 512 + SWZ(ks * 64 + lq * 16, n0));
        mfma32(acc[0], xf[0][ks], b0);
        mfma32(acc[1], xf[1][ks], b0);
      }
      #pragma unroll
      for (int mt = 0; mt < 2; ++mt)
        #pragma unroll
        for (int r = 0; r < 4; ++r) {
          int row = wr2 * 32 + mt * 16 + lq * 4 + r;
          int col = wc4 * 16 + lane15;
          *reinterpret_cast<uint16_t*>(dstb + row * 128 + SWZ(col * 2, row)) =
              (uint16_t)bf16rne(acc[mt][r]);
        }
    }
    __syncthreads();   // Q,K written; Wq/Wk tiles no longer needed

    // ---- stage Wv chunk (32KiB at XW+0) + W0 chunk (32KiB at XW+32K) ----
    #pragma unroll
    for (int it = 0; it < 4; ++it) {
      int idx = it * 1024 + tid;         // 0..4095
      if (idx < 2048) {
        int n = idx >> 5, seg = idx & 31;
        iv4 d = *reinterpret_cast<const iv4*>(
            reinterpret_cast<const char*>(WvT) + (size_t)(c0 + n) * 512 + seg * 16);
        *reinterpret_cast<iv4*>(XW + n * 512 + SWZ(seg * 16, n)) = d;
      } else {
        int x = idx - 2048;
        int n = x >> 3, seg = x & 7;     // W0^T row n, k-slice c0..c0+63
        iv4 d = *reinterpret_cast<const iv4*>(
            reinterpret_cast<const char*>(W0T) + (size_t)n * 512 + c0 * 2 + seg * 16);
        *reinterpret_cast<iv4*>(XW + 32768 + n * 128 + SWZ(seg * 16, n)) = d;
      }
    }
    __syncthreads();

    // ---- compute V projection ----
    {
      fv4 acc[2];
      acc[0] = fv4{0.f,0.f,0.f,0.f}; acc[1] = fv4{0.f,0.f,0.f,0.f};
      int n0 = wc4 * 16 + lane15;
      #pragma unroll
      for (int ks = 0; ks < 8; ++ks) {
        iv4 b0 = *reinterpret_cast<const iv4*>(XW + n0 * 512 + SWZ(ks * 64 + lq * 16, n0));
        mfma32(acc[0], xf[0][ks], b0);
        mfma32(acc[1], xf[1][ks], b0);
      }
      #pragma unroll
      for (int mt = 0; mt < 2; ++mt)
        #pragma unroll
        for (int r = 0; r < 4; ++r) {
          int row = wr2 * 32 + mt * 16 + lq * 4 + r;
          int col = wc4 * 16 + lane15;
          *reinterpret_cast<uint16_t*>(Vb + row * 128 + SWZ(col * 2, row)) =
              (uint16_t)bf16rne(acc[mt][r]);
        }
    }
    __syncthreads();   // Q/K/V all visible

    // ---- attention: 16 (group,head) pairs, 1 per wave ----
    {
      int g = w >> 1, hh = w & 1;
      int rowb = g * 16;
      int frow = rowb + lane15;
      // swapped QK^T: A = K (row=key), B = Q read row-major == Q^T B-layout
      iv4 kf = *reinterpret_cast<const iv4*>(Kb + frow * 128 + SWZ(hh * 64 + lq * 16, frow));
      iv4 qf = *reinterpret_cast<const iv4*>(Qb + frow * 128 + SWZ(hh * 64 + lq * 16, frow));
      fv4 s = fv4{0.f, 0.f, 0.f, 0.f};
      mfma32(s, kf, qf);                 // s[r] = S^T[key=lq*4+r][query=lane15]
      float mx = fmaxf(fmaxf(s[0], s[1]), fmaxf(s[2], s[3]));
      mx = fmaxf(mx, __shfl_xor(mx, 16));
      mx = fmaxf(mx, __shfl_xor(mx, 32));
      const float Cc = 0.25503373f;      // log2(e)/sqrt(32)
      float e0 = exp2f((s[0] - mx) * Cc), e1 = exp2f((s[1] - mx) * Cc);
      float e2 = exp2f((s[2] - mx) * Cc), e3 = exp2f((s[3] - mx) * Cc);
      float sum = e0 + e1 + e2 + e3;
      sum += __shfl_xor(sum, 16);
      sum += __shfl_xor(sum, 32);
      float inv = 1.0f / sum;
      iv2 pa; pa[0] = (int)pk2(bf16rne(e0 * inv), bf16rne(e1 * inv));
              pa[1] = (int)pk2(bf16rne(e2 * inv), bf16rne(e3 * inv));
      // PV: ctx[m][dv] via 16x16x16; P acc layout == A layout (no shuffles)
      #pragma unroll
      for (int dvt = 0; dvt < 2; ++dvt) {
        int col = hh * 32 + dvt * 16 + lane15;
        int r0 = rowb + lq * 4;
        uint32_t v0 = *reinterpret_cast<const uint16_t*>(Vb + (r0 + 0) * 128 + SWZ(col * 2, r0 + 0));
        uint32_t v1 = *reinterpret_cast<const uint16_t*>(Vb + (r0 + 1) * 128 + SWZ(col * 2, r0 + 1));
        uint32_t v2 = *reinterpret_cast<const uint16_t*>(Vb + (r0 + 2) * 128 + SWZ(col * 2, r0 + 2));
        uint32_t v3 = *reinterpret_cast<const uint16_t*>(Vb + (r0 + 3) * 128 + SWZ(col * 2, r0 + 3));
        iv2 bv; bv[0] = (int)pk2(v0, v1); bv[1] = (int)pk2(v2, v3);
        fv4 cacc = fv4{0.f, 0.f, 0.f, 0.f};
        mfma16(cacc, pa, bv);
        #pragma unroll
        for (int r = 0; r < 4; ++r) {
          int row = rowb + lq * 4 + r;
          *reinterpret_cast<uint16_t*>(Cb + row * 128 + SWZ(col * 2, row)) =
              (uint16_t)bf16rne(cacc[r]);
        }
      }
    }
    __syncthreads();   // ctx visible

    // ---- out += ctx_chunk @ W0[c0:c0+64, :]  (wave: 32 rows x 64 cols) ----
    #pragma unroll
    for (int ks = 0; ks < 2; ++ks) {
      iv4 af[2];
      #pragma unroll
      for (int mt = 0; mt < 2; ++mt) {
        int row = wr2 * 32 + mt * 16 + lane15;
        af[mt] = *reinterpret_cast<const iv4*>(Cb + row * 128 + SWZ(ks * 64 + lq * 16, row));
      }
      #pragma unroll
      for (int nt = 0; nt < 4; ++nt) {
        int n = wc4 * 64 + nt * 16 + lane15;
        iv4 bfg = *reinterpret_cast<const iv4*>(XW + 32768 + n * 128 + SWZ(ks * 64 + lq * 16, n));
        #pragma unroll
        for (int mt = 0; mt < 2; ++mt) mfma32(outacc[mt][nt], af[mt], bfg);
      }
    }
    __syncthreads();   // end of chunk: XW + Q/K/V/C all reusable
  } // hc

  // ---- scatter out (fp32, 64B segments per 16-lane group) ----
  #pragma unroll
  for (int mt = 0; mt < 2; ++mt) {
    int rb = wr2 * 32 + mt * 16 + lq * 4;
    int t0 = s2t[slot0 + rb + 0];
    int t1 = s2t[slot0 + rb + 1];
    int t2 = s2t[slot0 + rb + 2];
    int t3 = s2t[slot0 + rb + 3];
    #pragma unroll
    for (int nt = 0; nt < 4; ++nt) {
      int col = wc4 * 64 + nt * 16 + lane15;
      if (t0 >= 0) out[(size_t)t0 * E_ + col] = outacc[mt][nt][0];
      if (t1 >= 0) out[(size_t)t1 * E_ + col] = outacc[mt][nt][1];
      if (t2 >= 0) out[(size_t)t2 * E_ + col] = outacc[mt][nt][2];
      if (t3 >= 0) out[(size_t)t3 * E_ + col] = outacc[mt][nt][3];
    }
  }
}

extern "C" void kernel_launch(void* const* d_in, const int* in_sizes, int n_in,
                              void* d_out, int out_size, void* d_ws, size_t ws_size,
                              hipStream_t stream) {
  (void)in_sizes; (void)n_in; (void)out_size; (void)ws_size;
  const float* emb = (const float*)d_in[0];
  const float* Wq  = (const float*)d_in[1];
  const float* Wk  = (const float*)d_in[2];
  const float* Wv  = (const float*)d_in[3];
  const float* W0  = (const float*)d_in[4];
  const int*   pos = (const int*)d_in[5];
  float* out = (float*)d_out;

  // ws layout: cnt 32KB | s2t 512KB | WT(4x bf16 256x256) 512KB
  int* cnt = (int*)d_ws;
  int* s2t = (int*)((char*)d_ws + 32768);
  uint16_t* WT = (uint16_t*)((char*)d_ws + 32768 + 524288);

  (void)hipFuncSetAttribute(reinterpret_cast<const void*>(k_main),
                            hipFuncAttributeMaxDynamicSharedMemorySize, 131072);

  k_init <<<512, 256, 0, stream>>>(cnt, s2t);
  k_trans<<<dim3(256, 4), 256, 0, stream>>>(Wq, Wk, Wv, W0, WT);
  k_rank <<<512, 256, 0, stream>>>(pos, cnt, s2t);
  k_main <<<NWG, 1024, 131072, stream>>>(emb, s2t, WT, out);
}

// Round 4
// 274.491 us; speedup vs baseline: 1.7805x; 1.7805x over previous
//
#include <hip/hip_runtime.h>
#include <stdint.h>

// Problem constants (fixed instance)
#define B_    32
#define S_    4096
#define E_    256
#define P_    256
#define M_    16
#define G_    (B_*P_)      // 8192 groups
#define NSLOT (G_*M_)      // 131072 slots (== tokens)
#define GPW   4            // groups per workgroup
#define ROWS  64           // 4 groups * 16 slots
#define NWG   (G_/GPW)     // 2048 workgroups

typedef float fv4 __attribute__((ext_vector_type(4)));
typedef int   iv4 __attribute__((ext_vector_type(4)));
typedef int   iv2 __attribute__((ext_vector_type(2)));
typedef __bf16 bv8 __attribute__((ext_vector_type(8)));
typedef short  sv4 __attribute__((ext_vector_type(4)));

__device__ __forceinline__ uint32_t bf16rne(float f) {
  uint32_t u = __builtin_bit_cast(uint32_t, f);
  u += 0x7fffu + ((u >> 16) & 1u);
  return u >> 16;
}
__device__ __forceinline__ uint32_t pk2(uint32_t lo, uint32_t hi) {
  return (lo & 0xffffu) | (hi << 16);
}
// Builtins (NOT inline asm): hazard recognizer must see MFMAs (round-1 NaN).
__device__ __forceinline__ void mfma32(fv4& d, iv4 a, iv4 b) {
  d = __builtin_amdgcn_mfma_f32_16x16x32_bf16(
        __builtin_bit_cast(bv8, a), __builtin_bit_cast(bv8, b), d, 0, 0, 0);
}
__device__ __forceinline__ void mfma16(fv4& d, iv2 a, iv2 b) {
  d = __builtin_amdgcn_mfma_f32_16x16x16bf16_1k(
        __builtin_bit_cast(sv4, a), __builtin_bit_cast(sv4, b), d, 0, 0, 0);
}
// async global->LDS, 16B per lane; LDS dest = wave-uniform base + lane*16.
__device__ __forceinline__ void gload_lds16(const void* g, void* l) {
  __builtin_amdgcn_global_load_lds(
      (const __attribute__((address_space(1))) uint32_t*)g,
      (__attribute__((address_space(3))) uint32_t*)l, 16, 0, 0);
}

// XOR swizzle: flips byte bits 4-6 by row&7 (involution).
#define SWZ(off, row) ((off) ^ (((row) & 7) << 4))

// ---------------- prep kernels ----------------
__global__ void k_init(int* cnt, int* s2t) {
  int i = blockIdx.x * 256 + threadIdx.x;
  if (i < G_) cnt[i] = 0;
  if (i < NSLOT) s2t[i] = -1;
}

__global__ void k_trans(const float* __restrict__ Wq, const float* __restrict__ Wk,
                        const float* __restrict__ Wv, const float* __restrict__ W0,
                        uint16_t* __restrict__ WT) {
  // WT: 4 concatenated [256][256] bf16, WT[w][n][k] = bf16(W[w][k][n])
  int o = blockIdx.x * 256 + threadIdx.x;     // 0..65535
  int wsel = blockIdx.y;
  const float* W = (wsel == 0) ? Wq : (wsel == 1) ? Wk : (wsel == 2) ? Wv : W0;
  int n = o >> 8, k = o & 255;
  WT[(size_t)wsel * 65536 + o] = (uint16_t)bf16rne(W[k * 256 + n]);
}

__global__ void k_rank(const int* __restrict__ pos, int* cnt, int* s2t) {
  int i = blockIdx.x * 256 + threadIdx.x;
  if (i >= B_ * S_) return;
  int p = pos[i];
  if (p < 0 || p >= P_) return;          // invalid -> dropped (stays -1)
  int b = i >> 12;                       // i / S_
  int g = (b << 8) + p;
  int r = atomicAdd(&cnt[g], 1);         // arbitrary slot order: attention is
  if (r < M_) s2t[g * M_ + r] = i;       // permutation-equivariant, so OK
}

// ---------------- fused main kernel ----------------
// 1 WG = 4 groups = 64 rows, 512 threads = 8 waves; LDS 64 KiB -> 2 WGs/CU.
// Wave grid: mq = w>>1 (16-row block), nh = w&1 (col half).
// LDS: buf0 32K (X staging -> W tiles), Qb/Kb/Vb/Cb 8K each.
__global__ __launch_bounds__(512, 4) void k_main(
    const float* __restrict__ emb, const int* __restrict__ s2t,
    const uint16_t* __restrict__ WT, float* __restrict__ out) {
  extern __shared__ char smem[];
  char* buf0 = smem;           // 32 KiB
  char* Qb = smem + 32768;     // 8 KiB [64][128B], swizzled
  char* Kb = smem + 40960;
  char* Vb = smem + 49152;
  char* Cb = smem + 57344;

  const uint16_t* WqT = WT;
  const uint16_t* WkT = WT + 65536;
  const uint16_t* WvT = WT + 131072;
  const uint16_t* W0T = WT + 196608;

  const int tid = threadIdx.x;
  const int l = tid & 63;
  const int w = tid >> 6;           // wave 0..7
  const int lane15 = l & 15;
  const int lq = l >> 4;            // lane quad 0..3
  const int mq = w >> 1;            // 16-row block 0..3
  const int nh = w & 1;             // col half 0..1
  const int slot0 = blockIdx.x * ROWS;

  // ---- gather: 64 token rows -> bf16 X in buf0 (coalesced 1KB row loads) ----
  #pragma unroll
  for (int rl = 0; rl < 8; ++rl) {
    int row = w * 8 + rl;
    int t = s2t[slot0 + row];            // wave-uniform (scalar load)
    uint32_t u0 = 0, u1 = 0;
    if (t >= 0) {
      const float4 v = *reinterpret_cast<const float4*>(emb + (size_t)t * E_ + (l << 2));
      u0 = pk2(bf16rne(v.x), bf16rne(v.y));
      u1 = pk2(bf16rne(v.z), bf16rne(v.w));
    }
    iv2 val; val[0] = (int)u0; val[1] = (int)u1;
    *reinterpret_cast<iv2*>(buf0 + row * 512 + SWZ(l * 8, row)) = val;
  }
  __syncthreads();

  // ---- X A-fragments into registers: 8 k-steps, 16-row block (32 VGPR) ----
  iv4 xf[8];
  const int arow = mq * 16 + lane15;
  #pragma unroll
  for (int ks = 0; ks < 8; ++ks)
    xf[ks] = *reinterpret_cast<const iv4*>(buf0 + arow * 512 + SWZ(ks * 64 + lq * 16, arow));
  __syncthreads();   // buf0 now reusable for weight tiles

  fv4 outacc[8];     // 16 rows x 128 cols per wave, persists across chunks
  #pragma unroll
  for (int i = 0; i < 8; ++i) outacc[i] = fv4{0.f, 0.f, 0.f, 0.f};

  for (int hc = 0; hc < 4; ++hc) {       // 4 head-chunks of 64 cols (2 heads)
    const int c0 = hc * 64;

    // ---- Q/K/V projections (sequential staging through buf0) ----
    for (int wgt = 0; wgt < 3; ++wgt) {
      const uint16_t* Wt = (wgt == 0) ? WqT : (wgt == 1) ? WkT : WvT;
      char* dstb = (wgt == 0) ? Qb : (wgt == 1) ? Kb : Vb;
      // stage W^T rows c0..c0+63 (32 KiB) via global_load_lds, source
      // pre-swizzled so linear LDS dest lands in SWZ layout (involution).
      #pragma unroll
      for (int it = 0; it < 4; ++it) {
        int q = it * 8 + w;              // 1 KiB LDS block per wave-instr
        int n = q * 2 + (l >> 5);
        int seg = l & 31;
        gload_lds16(reinterpret_cast<const char*>(Wt) + (size_t)(c0 + n) * 512 + SWZ(seg * 16, n),
                    buf0 + q * 1024);
      }
      __syncthreads();                   // drains vmcnt -> tile resident
      fv4 acc0 = fv4{0.f,0.f,0.f,0.f}, acc1 = fv4{0.f,0.f,0.f,0.f};
      const int n0 = nh * 32 + lane15, n1 = n0 + 16;
      #pragma unroll
      for (int ks = 0; ks < 8; ++ks) {
        iv4 b0 = *reinterpret_cast<const iv4*>(buf0 + n0 * 512 + SWZ(ks * 64 + lq * 16, n0));
        iv4 b1 = *reinterpret_cast<const iv4*>(buf0 + n1 * 512 + SWZ(ks * 64 + lq * 16, n1));
        mfma32(acc0, xf[ks], b0);
        mfma32(acc1, xf[ks], b1);
      }
      #pragma unroll
      for (int r = 0; r < 4; ++r) {
        int row = mq * 16 + lq * 4 + r;
        int col0 = nh * 32 + lane15;
        *reinterpret_cast<uint16_t*>(dstb + row * 128 + SWZ(col0 * 2, row)) =
            (uint16_t)bf16rne(acc0[r]);
        *reinterpret_cast<uint16_t*>(dstb + row * 128 + SWZ((col0 + 16) * 2, row)) =
            (uint16_t)bf16rne(acc1[r]);
      }
      __syncthreads();                   // buf0 readers done before next stage
    }

    // ---- stage W0 k-slice (async, overlaps attention) ----
    #pragma unroll
    for (int it = 0; it < 4; ++it) {
      int q = it * 8 + w;
      int n = q * 8 + (l >> 3);          // W0 row (output col) 0..255
      int seg = l & 7;
      gload_lds16(reinterpret_cast<const char*>(W0T) + (size_t)n * 512 + (size_t)c0 * 2 + SWZ(seg * 16, n),
                  buf0 + q * 1024);
    }

    // ---- attention: 8 (group,head) pairs, 1 per wave ----
    {
      int g = w >> 1, hh = w & 1;
      int rowb = g * 16;
      int frow = rowb + lane15;
      // swapped QK^T: A = K (row=key), B = Q read row-major == Q^T B-layout
      iv4 kf = *reinterpret_cast<const iv4*>(Kb + frow * 128 + SWZ(hh * 64 + lq * 16, frow));
      iv4 qf = *reinterpret_cast<const iv4*>(Qb + frow * 128 + SWZ(hh * 64 + lq * 16, frow));
      fv4 s = fv4{0.f, 0.f, 0.f, 0.f};
      mfma32(s, kf, qf);                 // s[r] = S^T[key=lq*4+r][query=lane15]
      float mx = fmaxf(fmaxf(s[0], s[1]), fmaxf(s[2], s[3]));
      mx = fmaxf(mx, __shfl_xor(mx, 16));
      mx = fmaxf(mx, __shfl_xor(mx, 32));
      const float Cc = 0.25503373f;      // log2(e)/sqrt(32)
      float e0 = exp2f((s[0] - mx) * Cc), e1 = exp2f((s[1] - mx) * Cc);
      float e2 = exp2f((s[2] - mx) * Cc), e3 = exp2f((s[3] - mx) * Cc);
      float sum = e0 + e1 + e2 + e3;
      sum += __shfl_xor(sum, 16);
      sum += __shfl_xor(sum, 32);
      float inv = 1.0f / sum;
      iv2 pa; pa[0] = (int)pk2(bf16rne(e0 * inv), bf16rne(e1 * inv));
              pa[1] = (int)pk2(bf16rne(e2 * inv), bf16rne(e3 * inv));
      // PV: ctx[m][dv] via 16x16x16; P acc layout == A layout (no shuffles)
      #pragma unroll
      for (int dvt = 0; dvt < 2; ++dvt) {
        int col = hh * 32 + dvt * 16 + lane15;
        int r0 = rowb + lq * 4;
        uint32_t v0 = *reinterpret_cast<const uint16_t*>(Vb + (r0 + 0) * 128 + SWZ(col * 2, r0 + 0));
        uint32_t v1 = *reinterpret_cast<const uint16_t*>(Vb + (r0 + 1) * 128 + SWZ(col * 2, r0 + 1));
        uint32_t v2 = *reinterpret_cast<const uint16_t*>(Vb + (r0 + 2) * 128 + SWZ(col * 2, r0 + 2));
        uint32_t v3 = *reinterpret_cast<const uint16_t*>(Vb + (r0 + 3) * 128 + SWZ(col * 2, r0 + 3));
        iv2 bv; bv[0] = (int)pk2(v0, v1); bv[1] = (int)pk2(v2, v3);
        fv4 cacc = fv4{0.f, 0.f, 0.f, 0.f};
        mfma16(cacc, pa, bv);
        #pragma unroll
        for (int r = 0; r < 4; ++r) {
          int row = rowb + lq * 4 + r;
          *reinterpret_cast<uint16_t*>(Cb + row * 128 + SWZ(col * 2, row)) =
              (uint16_t)bf16rne(cacc[r]);
        }
      }
    }
    __syncthreads();   // ctx visible; W0 tile resident (vmcnt drained)

    // ---- out += ctx_chunk @ W0[c0:c0+64, :]  (wave: 16 rows x 128 cols) ----
    #pragma unroll
    for (int ks = 0; ks < 2; ++ks) {
      int row = mq * 16 + lane15;
      iv4 af = *reinterpret_cast<const iv4*>(Cb + row * 128 + SWZ(ks * 64 + lq * 16, row));
      #pragma unroll
      for (int nt = 0; nt < 8; ++nt) {
        int n = nh * 128 + nt * 16 + lane15;
        iv4 bfg = *reinterpret_cast<const iv4*>(buf0 + n * 128 + SWZ(ks * 64 + lq * 16, n));
        mfma32(outacc[nt], af, bfg);
      }
    }
    __syncthreads();   // end of chunk: buf0/QKV/Cb reusable
  } // hc

  // ---- scatter out (fp32, 64B segments per 16-lane group) ----
  #pragma unroll
  for (int r = 0; r < 4; ++r) {
    int t = s2t[slot0 + mq * 16 + lq * 4 + r];
    if (t < 0) continue;
    #pragma unroll
    for (int nt = 0; nt < 8; ++nt) {
      int col = nh * 128 + nt * 16 + lane15;
      out[(size_t)t * E_ + col] = outacc[nt][r];
    }
  }
}

extern "C" void kernel_launch(void* const* d_in, const int* in_sizes, int n_in,
                              void* d_out, int out_size, void* d_ws, size_t ws_size,
                              hipStream_t stream) {
  (void)in_sizes; (void)n_in; (void)out_size; (void)ws_size;
  const float* emb = (const float*)d_in[0];
  const float* Wq  = (const float*)d_in[1];
  const float* Wk  = (const float*)d_in[2];
  const float* Wv  = (const float*)d_in[3];
  const float* W0  = (const float*)d_in[4];
  const int*   pos = (const int*)d_in[5];
  float* out = (float*)d_out;

  // ws layout: cnt 32KB | s2t 512KB | WT(4x bf16 256x256) 512KB
  int* cnt = (int*)d_ws;
  int* s2t = (int*)((char*)d_ws + 32768);
  uint16_t* WT = (uint16_t*)((char*)d_ws + 32768 + 524288);

  (void)hipFuncSetAttribute(reinterpret_cast<const void*>(k_main),
                            hipFuncAttributeMaxDynamicSharedMemorySize, 65536);

  k_init <<<512, 256, 0, stream>>>(cnt, s2t);
  k_trans<<<dim3(256, 4), 256, 0, stream>>>(Wq, Wk, Wv, W0, WT);
  k_rank <<<512, 256, 0, stream>>>(pos, cnt, s2t);
  k_main <<<NWG, 512, 65536, stream>>>(emb, s2t, WT, out);
}

// Round 5
// 220.343 us; speedup vs baseline: 2.2180x; 1.2457x over previous
//
#include <hip/hip_runtime.h>
#include <stdint.h>

// Problem constants (fixed instance)
#define B_    32
#define S_    4096
#define E_    256
#define P_    256
#define M_    16
#define G_    (B_*P_)      // 8192 groups
#define NSLOT (G_*M_)      // 131072 slots (== tokens)
#define GPW   4            // groups per workgroup
#define ROWS  64           // 4 groups * 16 slots
#define NWG   (G_/GPW)     // 2048 workgroups

typedef float fv4 __attribute__((ext_vector_type(4)));
typedef int   iv4 __attribute__((ext_vector_type(4)));
typedef int   iv2 __attribute__((ext_vector_type(2)));
typedef __bf16 bv8 __attribute__((ext_vector_type(8)));
typedef short  sv4 __attribute__((ext_vector_type(4)));

__device__ __forceinline__ uint32_t bf16rne(float f) {
  uint32_t u = __builtin_bit_cast(uint32_t, f);
  u += 0x7fffu + ((u >> 16) & 1u);
  return u >> 16;
}
__device__ __forceinline__ uint32_t pk2(uint32_t lo, uint32_t hi) {
  return (lo & 0xffffu) | (hi << 16);
}
// Builtins (NOT inline asm): hazard recognizer must see MFMAs (round-1 NaN).
__device__ __forceinline__ void mfma32(fv4& d, iv4 a, iv4 b) {
  d = __builtin_amdgcn_mfma_f32_16x16x32_bf16(
        __builtin_bit_cast(bv8, a), __builtin_bit_cast(bv8, b), d, 0, 0, 0);
}
__device__ __forceinline__ void mfma16(fv4& d, iv2 a, iv2 b) {
  d = __builtin_amdgcn_mfma_f32_16x16x16bf16_1k(
        __builtin_bit_cast(sv4, a), __builtin_bit_cast(sv4, b), d, 0, 0, 0);
}
// async global->LDS, 16B per lane; LDS dest = wave-uniform base + lane*16.
__device__ __forceinline__ void gload_lds16(const void* g, void* l) {
  __builtin_amdgcn_global_load_lds(
      (const __attribute__((address_space(1))) uint32_t*)g,
      (__attribute__((address_space(3))) uint32_t*)l, 16, 0, 0);
}

// XOR swizzle: flips byte bits 4-6 by row&7 (involution).
#define SWZ(off, row) ((off) ^ (((row) & 7) << 4))

// ---------------- prep kernels ----------------
__global__ void k_init(int* cnt, int* s2t) {
  int i = blockIdx.x * 256 + threadIdx.x;
  if (i < G_) cnt[i] = 0;
  if (i < NSLOT) s2t[i] = -1;
}

__global__ void k_trans(const float* __restrict__ Wq, const float* __restrict__ Wk,
                        const float* __restrict__ Wv, const float* __restrict__ W0,
                        uint16_t* __restrict__ WT) {
  // WT: 4 concatenated [256][256] bf16, WT[w][n][k] = bf16(W[w][k][n])
  int o = blockIdx.x * 256 + threadIdx.x;     // 0..65535
  int wsel = blockIdx.y;
  const float* W = (wsel == 0) ? Wq : (wsel == 1) ? Wk : (wsel == 2) ? Wv : W0;
  int n = o >> 8, k = o & 255;
  WT[(size_t)wsel * 65536 + o] = (uint16_t)bf16rne(W[k * 256 + n]);
}

__global__ void k_rank(const int* __restrict__ pos, int* cnt, int* s2t) {
  int i = blockIdx.x * 256 + threadIdx.x;
  if (i >= B_ * S_) return;
  int p = pos[i];
  if (p < 0 || p >= P_) return;          // invalid -> dropped (stays -1)
  int b = i >> 12;                       // i / S_
  int g = (b << 8) + p;
  int r = atomicAdd(&cnt[g], 1);         // arbitrary slot order: attention is
  if (r < M_) s2t[g * M_ + r] = i;       // permutation-equivariant, so OK
}

// ---------------- fused main kernel ----------------
// 1 WG = 4 groups = 64 rows, 512 threads = 8 waves; LDS 64 KiB -> 2 WGs/CU.
// __launch_bounds__ 2nd arg is honored as min BLOCKS/CU (CUDA semantics;
// measured: (512,4) gave VGPR=64 = 512/(4blk*2w/SIMD) and spilled ~400MB).
// (512,2): 2 blk * 8 waves = 16 waves/CU = 4/SIMD -> 128 unified regs/wave.
// LDS: buf0 32K (X staging -> W tiles), Qb/Kb/Vb/Cb 8K each.
__global__ __launch_bounds__(512, 2) void k_main(
    const float* __restrict__ emb, const int* __restrict__ s2t,
    const uint16_t* __restrict__ WT, float* __restrict__ out) {
  extern __shared__ char smem[];
  char* buf0 = smem;           // 32 KiB
  char* Qb = smem + 32768;     // 8 KiB [64][128B], swizzled
  char* Kb = smem + 40960;
  char* Vb = smem + 49152;
  char* Cb = smem + 57344;

  const uint16_t* WqT = WT;
  const uint16_t* WkT = WT + 65536;
  const uint16_t* WvT = WT + 131072;
  const uint16_t* W0T = WT + 196608;

  const int tid = threadIdx.x;
  const int l = tid & 63;
  const int w = tid >> 6;           // wave 0..7
  const int lane15 = l & 15;
  const int lq = l >> 4;            // lane quad 0..3
  const int mq = w >> 1;            // 16-row block 0..3
  const int nh = w & 1;             // col half 0..1
  const int slot0 = blockIdx.x * ROWS;

  // ---- gather: 64 token rows -> bf16 X in buf0 (coalesced 1KB row loads) ----
  // unroll 2: cap in-flight float4 loads so prologue isn't the VGPR high-water
  #pragma unroll 2
  for (int rl = 0; rl < 8; ++rl) {
    int row = w * 8 + rl;
    int t = s2t[slot0 + row];            // wave-uniform (scalar load)
    uint32_t u0 = 0, u1 = 0;
    if (t >= 0) {
      const float4 v = *reinterpret_cast<const float4*>(emb + (size_t)t * E_ + (l << 2));
      u0 = pk2(bf16rne(v.x), bf16rne(v.y));
      u1 = pk2(bf16rne(v.z), bf16rne(v.w));
    }
    iv2 val; val[0] = (int)u0; val[1] = (int)u1;
    *reinterpret_cast<iv2*>(buf0 + row * 512 + SWZ(l * 8, row)) = val;
  }
  __syncthreads();

  // ---- X A-fragments into registers: 8 k-steps, 16-row block (32 VGPR) ----
  iv4 xf[8];
  const int arow = mq * 16 + lane15;
  #pragma unroll
  for (int ks = 0; ks < 8; ++ks)
    xf[ks] = *reinterpret_cast<const iv4*>(buf0 + arow * 512 + SWZ(ks * 64 + lq * 16, arow));
  __syncthreads();   // buf0 now reusable for weight tiles

  fv4 outacc[8];     // 16 rows x 128 cols per wave, persists across chunks
  #pragma unroll
  for (int i = 0; i < 8; ++i) outacc[i] = fv4{0.f, 0.f, 0.f, 0.f};

  for (int hc = 0; hc < 4; ++hc) {       // 4 head-chunks of 64 cols (2 heads)
    const int c0 = hc * 64;

    // ---- Q/K/V projections (sequential staging through buf0) ----
    for (int wgt = 0; wgt < 3; ++wgt) {
      const uint16_t* Wt = (wgt == 0) ? WqT : (wgt == 1) ? WkT : WvT;
      char* dstb = (wgt == 0) ? Qb : (wgt == 1) ? Kb : Vb;
      // stage W^T rows c0..c0+63 (32 KiB) via global_load_lds, source
      // pre-swizzled so linear LDS dest lands in SWZ layout (involution).
      #pragma unroll
      for (int it = 0; it < 4; ++it) {
        int q = it * 8 + w;              // 1 KiB LDS block per wave-instr
        int n = q * 2 + (l >> 5);
        int seg = l & 31;
        gload_lds16(reinterpret_cast<const char*>(Wt) + (size_t)(c0 + n) * 512 + SWZ(seg * 16, n),
                    buf0 + q * 1024);
      }
      __syncthreads();                   // drains vmcnt -> tile resident
      fv4 acc0 = fv4{0.f,0.f,0.f,0.f}, acc1 = fv4{0.f,0.f,0.f,0.f};
      const int n0 = nh * 32 + lane15, n1 = n0 + 16;
      #pragma unroll
      for (int ks = 0; ks < 8; ++ks) {
        iv4 b0 = *reinterpret_cast<const iv4*>(buf0 + n0 * 512 + SWZ(ks * 64 + lq * 16, n0));
        iv4 b1 = *reinterpret_cast<const iv4*>(buf0 + n1 * 512 + SWZ(ks * 64 + lq * 16, n1));
        mfma32(acc0, xf[ks], b0);
        mfma32(acc1, xf[ks], b1);
      }
      #pragma unroll
      for (int r = 0; r < 4; ++r) {
        int row = mq * 16 + lq * 4 + r;
        int col0 = nh * 32 + lane15;
        *reinterpret_cast<uint16_t*>(dstb + row * 128 + SWZ(col0 * 2, row)) =
            (uint16_t)bf16rne(acc0[r]);
        *reinterpret_cast<uint16_t*>(dstb + row * 128 + SWZ((col0 + 16) * 2, row)) =
            (uint16_t)bf16rne(acc1[r]);
      }
      __syncthreads();                   // buf0 readers done before next stage
    }

    // ---- stage W0 k-slice (async, overlaps attention) ----
    #pragma unroll
    for (int it = 0; it < 4; ++it) {
      int q = it * 8 + w;
      int n = q * 8 + (l >> 3);          // W0 row (output col) 0..255
      int seg = l & 7;
      gload_lds16(reinterpret_cast<const char*>(W0T) + (size_t)n * 512 + (size_t)c0 * 2 + SWZ(seg * 16, n),
                  buf0 + q * 1024);
    }

    // ---- attention: 8 (group,head) pairs, 1 per wave ----
    {
      int g = w >> 1, hh = w & 1;
      int rowb = g * 16;
      int frow = rowb + lane15;
      // swapped QK^T: A = K (row=key), B = Q read row-major == Q^T B-layout
      iv4 kf = *reinterpret_cast<const iv4*>(Kb + frow * 128 + SWZ(hh * 64 + lq * 16, frow));
      iv4 qf = *reinterpret_cast<const iv4*>(Qb + frow * 128 + SWZ(hh * 64 + lq * 16, frow));
      fv4 s = fv4{0.f, 0.f, 0.f, 0.f};
      mfma32(s, kf, qf);                 // s[r] = S^T[key=lq*4+r][query=lane15]
      float mx = fmaxf(fmaxf(s[0], s[1]), fmaxf(s[2], s[3]));
      mx = fmaxf(mx, __shfl_xor(mx, 16));
      mx = fmaxf(mx, __shfl_xor(mx, 32));
      const float Cc = 0.25503373f;      // log2(e)/sqrt(32)
      float e0 = exp2f((s[0] - mx) * Cc), e1 = exp2f((s[1] - mx) * Cc);
      float e2 = exp2f((s[2] - mx) * Cc), e3 = exp2f((s[3] - mx) * Cc);
      float sum = e0 + e1 + e2 + e3;
      sum += __shfl_xor(sum, 16);
      sum += __shfl_xor(sum, 32);
      float inv = 1.0f / sum;
      iv2 pa; pa[0] = (int)pk2(bf16rne(e0 * inv), bf16rne(e1 * inv));
              pa[1] = (int)pk2(bf16rne(e2 * inv), bf16rne(e3 * inv));
      // PV: ctx[m][dv] via 16x16x16; P acc layout == A layout (no shuffles)
      #pragma unroll
      for (int dvt = 0; dvt < 2; ++dvt) {
        int col = hh * 32 + dvt * 16 + lane15;
        int r0 = rowb + lq * 4;
        uint32_t v0 = *reinterpret_cast<const uint16_t*>(Vb + (r0 + 0) * 128 + SWZ(col * 2, r0 + 0));
        uint32_t v1 = *reinterpret_cast<const uint16_t*>(Vb + (r0 + 1) * 128 + SWZ(col * 2, r0 + 1));
        uint32_t v2 = *reinterpret_cast<const uint16_t*>(Vb + (r0 + 2) * 128 + SWZ(col * 2, r0 + 2));
        uint32_t v3 = *reinterpret_cast<const uint16_t*>(Vb + (r0 + 3) * 128 + SWZ(col * 2, r0 + 3));
        iv2 bv; bv[0] = (int)pk2(v0, v1); bv[1] = (int)pk2(v2, v3);
        fv4 cacc = fv4{0.f, 0.f, 0.f, 0.f};
        mfma16(cacc, pa, bv);
        #pragma unroll
        for (int r = 0; r < 4; ++r) {
          int row = rowb + lq * 4 + r;
          *reinterpret_cast<uint16_t*>(Cb + row * 128 + SWZ(col * 2, row)) =
              (uint16_t)bf16rne(cacc[r]);
        }
      }
    }
    __syncthreads();   // ctx visible; W0 tile resident (vmcnt drained)

    // ---- out += ctx_chunk @ W0[c0:c0+64, :]  (wave: 16 rows x 128 cols) ----
    #pragma unroll
    for (int ks = 0; ks < 2; ++ks) {
      int row = mq * 16 + lane15;
      iv4 af = *reinterpret_cast<const iv4*>(Cb + row * 128 + SWZ(ks * 64 + lq * 16, row));
      #pragma unroll
      for (int nt = 0; nt < 8; ++nt) {
        int n = nh * 128 + nt * 16 + lane15;
        iv4 bfg = *reinterpret_cast<const iv4*>(buf0 + n * 128 + SWZ(ks * 64 + lq * 16, n));
        mfma32(outacc[nt], af, bfg);
      }
    }
    __syncthreads();   // end of chunk: buf0/QKV/Cb reusable
  } // hc

  // ---- scatter out (fp32, 64B segments per 16-lane group) ----
  #pragma unroll
  for (int r = 0; r < 4; ++r) {
    int t = s2t[slot0 + mq * 16 + lq * 4 + r];
    if (t < 0) continue;
    #pragma unroll
    for (int nt = 0; nt < 8; ++nt) {
      int col = nh * 128 + nt * 16 + lane15;
      out[(size_t)t * E_ + col] = outacc[nt][r];
    }
  }
}

extern "C" void kernel_launch(void* const* d_in, const int* in_sizes, int n_in,
                              void* d_out, int out_size, void* d_ws, size_t ws_size,
                              hipStream_t stream) {
  (void)in_sizes; (void)n_in; (void)out_size; (void)ws_size;
  const float* emb = (const float*)d_in[0];
  const float* Wq  = (const float*)d_in[1];
  const float* Wk  = (const float*)d_in[2];
  const float* Wv  = (const float*)d_in[3];
  const float* W0  = (const float*)d_in[4];
  const int*   pos = (const int*)d_in[5];
  float* out = (float*)d_out;

  // ws layout: cnt 32KB | s2t 512KB | WT(4x bf16 256x256) 512KB
  int* cnt = (int*)d_ws;
  int* s2t = (int*)((char*)d_ws + 32768);
  uint16_t* WT = (uint16_t*)((char*)d_ws + 32768 + 524288);

  (void)hipFuncSetAttribute(reinterpret_cast<const void*>(k_main),
                            hipFuncAttributeMaxDynamicSharedMemorySize, 65536);

  k_init <<<512, 256, 0, stream>>>(cnt, s2t);
  k_trans<<<dim3(256, 4), 256, 0, stream>>>(Wq, Wk, Wv, W0, WT);
  k_rank <<<512, 256, 0, stream>>>(pos, cnt, s2t);
  k_main <<<NWG, 512, 65536, stream>>>(emb, s2t, WT, out);
}

// Round 6
// 178.774 us; speedup vs baseline: 2.7337x; 1.2325x over previous
//
#include <hip/hip_runtime.h>
#include <stdint.h>

// Problem constants (fixed instance)
#define B_    32
#define S_    4096
#define E_    256
#define P_    256
#define M_    16
#define G_    (B_*P_)      // 8192 groups
#define NSLOT (G_*M_)      // 131072 slots (== tokens)
#define GPW   8            // groups per workgroup
#define ROWS  128          // 8 groups * 16 slots
#define NWG   (G_/GPW)     // 1024 workgroups

typedef float fv4 __attribute__((ext_vector_type(4)));
typedef int   iv4 __attribute__((ext_vector_type(4)));
typedef int   iv2 __attribute__((ext_vector_type(2)));
typedef __bf16 bv8 __attribute__((ext_vector_type(8)));
typedef short  sv4 __attribute__((ext_vector_type(4)));

__device__ __forceinline__ uint32_t bf16rne(float f) {
  uint32_t u = __builtin_bit_cast(uint32_t, f);
  u += 0x7fffu + ((u >> 16) & 1u);
  return u >> 16;
}
__device__ __forceinline__ uint32_t pk2(uint32_t lo, uint32_t hi) {
  return (lo & 0xffffu) | (hi << 16);
}
// Builtins (NOT inline asm): hazard recognizer must see MFMAs (round-1 NaN).
__device__ __forceinline__ void mfma32(fv4& d, iv4 a, iv4 b) {
  d = __builtin_amdgcn_mfma_f32_16x16x32_bf16(
        __builtin_bit_cast(bv8, a), __builtin_bit_cast(bv8, b), d, 0, 0, 0);
}
__device__ __forceinline__ void mfma16(fv4& d, iv2 a, iv2 b) {
  d = __builtin_amdgcn_mfma_f32_16x16x16bf16_1k(
        __builtin_bit_cast(sv4, a), __builtin_bit_cast(sv4, b), d, 0, 0, 0);
}
// async global->LDS, 16B/lane; LDS dest = wave-uniform base + lane*16.
__device__ __forceinline__ void gload_lds16(const void* g, void* l) {
  __builtin_amdgcn_global_load_lds(
      (const __attribute__((address_space(1))) uint32_t*)g,
      (__attribute__((address_space(3))) uint32_t*)l, 16, 0, 0);
}

// XOR swizzle for 512B rows: flips byte bits 4-6 by row&7 (involution).
#define SWZ(off, row) ((off) ^ (((row) & 7) << 4))
// 64B-row buffers stored as [pair][128B], swizzled by pair&7 (bits 4-6).
#define LQKV(row, cb) ( ((row) >> 1) * 128 + \
    (((((row) & 1) << 6) + (cb)) ^ ((((row) >> 1) & 7) << 4)) )

// Raw barrier + counted waits (T3/T4): loads stay in flight across barriers.
#define BAR()   { asm volatile("" ::: "memory"); __builtin_amdgcn_s_barrier(); \
                  asm volatile("" ::: "memory"); }
#define VMWAIT2 asm volatile("s_waitcnt vmcnt(2)" ::: "memory")
#define VMWAIT0 asm volatile("s_waitcnt vmcnt(0)" ::: "memory")
#define LGKM0   asm volatile("s_waitcnt lgkmcnt(0)" ::: "memory")

// ---------------- prep kernels ----------------
__global__ void k_init(int* cnt, int* s2t) {
  int i = blockIdx.x * 256 + threadIdx.x;
  if (i < G_) cnt[i] = 0;
  if (i < NSLOT) s2t[i] = -1;
}

__global__ void k_trans(const float* __restrict__ Wq, const float* __restrict__ Wk,
                        const float* __restrict__ Wv, const float* __restrict__ W0,
                        uint16_t* __restrict__ WT) {
  // WT: 4 concatenated [256][256] bf16, WT[w][n][k] = bf16(W[w][k][n])
  int o = blockIdx.x * 256 + threadIdx.x;     // 0..65535
  int wsel = blockIdx.y;
  const float* W = (wsel == 0) ? Wq : (wsel == 1) ? Wk : (wsel == 2) ? Wv : W0;
  int n = o >> 8, k = o & 255;
  WT[(size_t)wsel * 65536 + o] = (uint16_t)bf16rne(W[k * 256 + n]);
}

__global__ void k_rank(const int* __restrict__ pos, int* cnt, int* s2t) {
  int i = blockIdx.x * 256 + threadIdx.x;
  if (i >= B_ * S_) return;
  int p = pos[i];
  if (p < 0 || p >= P_) return;          // invalid -> dropped (stays -1)
  int b = i >> 12;                       // i / S_
  int g = (b << 8) + p;
  int r = atomicAdd(&cnt[g], 1);         // arbitrary slot order: attention is
  if (r < M_) s2t[g * M_ + r] = i;       // permutation-equivariant, so OK
}

// stage one QKV weight tile: rows c0..c0+31 of WT (16 KiB), src pre-swizzled.
__device__ __forceinline__ void stage_qkv(const uint16_t* Wt, int c0, char* buf,
                                          int w, int l) {
  #pragma unroll
  for (int it = 0; it < 2; ++it) {
    int q = it * 8 + w;                  // 0..15, 1 KiB per instr
    int n = q * 2 + (l >> 5);            // local n-row 0..31
    int seg = l & 31;
    gload_lds16(reinterpret_cast<const char*>(Wt) + (size_t)(c0 + n) * 512 + SWZ(seg * 16, n),
                buf + q * 1024);
  }
}
// stage W0 k-slice tile: [256 n][64B], stored [128 pair][128B] pair-swizzled.
__device__ __forceinline__ void stage_w0(const uint16_t* W0T, int c0, char* buf,
                                         int w, int l) {
  #pragma unroll
  for (int it = 0; it < 2; ++it) {
    int q = it * 8 + w;
    int pair = q * 8 + (l >> 3);         // 0..127
    int jp = ((l & 7) * 16) ^ ((pair & 7) << 4);
    int n = 2 * pair + (jp >> 6);
    gload_lds16(reinterpret_cast<const char*>(W0T) + (size_t)n * 512 + c0 * 2 + (jp & 63),
                buf + q * 1024);
  }
}

// ---------------- fused main kernel ----------------
// 1 WG = 8 groups = 128 rows, 512 threads = 8 waves. LDS 64 KiB.
// Chunk = 32 cols (1 head); tile stream Wq,Wk,Wv,W0 per chunk, 2-deep
// ping-pong (bufA/bufB) with counted vmcnt so loads span barriers.
// Ledger: each stage = 2 instrs/wave; invariant at slot entry: own
// outstanding = 4 (tiles t, t+1); VMWAIT2 completes tile t for all waves
// after BAR; buffers only overwritten after post-compute BAR.
__global__ __launch_bounds__(512, 2) void k_main(
    const float* __restrict__ emb, const int* __restrict__ s2t,
    const uint16_t* __restrict__ WT, float* __restrict__ out) {
  extern __shared__ char smem[];
  char* bufA = smem;            // 16 KiB
  char* bufB = smem + 16384;    // 16 KiB
  char* Qb = smem + 32768;      // 8 KiB [128 rows][32 cols] bf16, pair-swizzled
  char* Kb = smem + 40960;
  char* Vb = smem + 49152;
  char* Cb = smem + 57344;

  const uint16_t* WqT = WT;
  const uint16_t* WkT = WT + 65536;
  const uint16_t* WvT = WT + 131072;
  const uint16_t* W0T = WT + 196608;

  const int tid = threadIdx.x;
  const int l = tid & 63;
  const int w = tid >> 6;           // wave 0..7
  const int lane15 = l & 15;
  const int lq = l >> 4;            // lane quad 0..3
  const int mq2 = w >> 1;           // 32-row block (W0/out phase)
  const int nh = w & 1;             // out col half
  const int slot0 = blockIdx.x * ROWS;

  // ---- gather: 128 token rows -> bf16 X overlay on all 64 KiB ----
  #pragma unroll 2
  for (int rl = 0; rl < 16; ++rl) {
    int row = w * 16 + rl;
    int t = s2t[slot0 + row];            // wave-uniform (scalar load)
    uint32_t u0 = 0, u1 = 0;
    if (t >= 0) {
      const float4 v = *reinterpret_cast<const float4*>(emb + (size_t)t * E_ + (l << 2));
      u0 = pk2(bf16rne(v.x), bf16rne(v.y));
      u1 = pk2(bf16rne(v.z), bf16rne(v.w));
    }
    iv2 val; val[0] = (int)u0; val[1] = (int)u1;
    *reinterpret_cast<iv2*>(smem + row * 512 + SWZ(l * 8, row)) = val;
  }
  __syncthreads();

  // ---- X A-fragments: wave w owns rows w*16..+16, full K (32 VGPR) ----
  iv4 xf[8];
  const int arow = w * 16 + lane15;
  #pragma unroll
  for (int ks = 0; ks < 8; ++ks)
    xf[ks] = *reinterpret_cast<const iv4*>(smem + arow * 512 + SWZ(ks * 64 + lq * 16, arow));
  __syncthreads();   // all xf read; overlay region now reusable

  fv4 outacc[2][8];  // 32 rows x 128 cols per wave, persists across chunks
  #pragma unroll
  for (int a = 0; a < 2; ++a)
    #pragma unroll
    for (int b = 0; b < 8; ++b) outacc[a][b] = fv4{0.f, 0.f, 0.f, 0.f};

  // prologue: 2 tiles in flight
  stage_qkv(WqT, 0, bufA, w, l);
  stage_qkv(WkT, 0, bufB, w, l);

  for (int hc = 0; hc < 8; ++hc) {       // 8 chunks of 32 cols (1 head)
    const int c0 = hc * 32;

    // QKV projection compute: wave w: 16 rows x 32 cols from tile in `buf`
    #define COMPUTE_QKV(buf, dst)                                            \
    {                                                                        \
      fv4 a0 = fv4{0.f,0.f,0.f,0.f}, a1 = fv4{0.f,0.f,0.f,0.f};              \
      const int n0 = lane15, n1 = lane15 + 16;                               \
      _Pragma("unroll")                                                      \
      for (int ks = 0; ks < 8; ++ks) {                                       \
        iv4 b0 = *reinterpret_cast<const iv4*>((buf) + n0 * 512 + SWZ(ks * 64 + lq * 16, n0)); \
        iv4 b1 = *reinterpret_cast<const iv4*>((buf) + n1 * 512 + SWZ(ks * 64 + lq * 16, n1)); \
        mfma32(a0, xf[ks], b0);                                              \
        mfma32(a1, xf[ks], b1);                                              \
      }                                                                      \
      _Pragma("unroll")                                                      \
      for (int r = 0; r < 4; ++r) {                                          \
        int row = w * 16 + lq * 4 + r;                                       \
        *reinterpret_cast<uint16_t*>((dst) + LQKV(row, lane15 * 2)) =        \
            (uint16_t)bf16rne(a0[r]);                                        \
        *reinterpret_cast<uint16_t*>((dst) + LQKV(row, (lane15 + 16) * 2)) = \
            (uint16_t)bf16rne(a1[r]);                                        \
      }                                                                      \
    }

    // slot 0: Wq tile in bufA
    VMWAIT2; BAR();
    COMPUTE_QKV(bufA, Qb);
    LGKM0; BAR();
    stage_qkv(WvT, c0, bufA, w, l);      // issue Wv(hc)

    // slot 1: Wk tile in bufB
    VMWAIT2; BAR();
    COMPUTE_QKV(bufB, Kb);
    LGKM0; BAR();
    stage_w0(W0T, c0, bufB, w, l);       // issue W0(hc)

    // slot 2: Wv tile in bufA
    VMWAIT2; BAR();
    COMPUTE_QKV(bufA, Vb);
    LGKM0; BAR();
    if (hc < 7) stage_qkv(WqT, c0 + 32, bufA, w, l);   // issue Wq(hc+1)

    // ---- attention (no tile): group g = w, head = hc ----
    {
      const int frow = w * 16 + lane15;
      iv4 kf = *reinterpret_cast<const iv4*>(Kb + LQKV(frow, lq * 16));
      iv4 qf = *reinterpret_cast<const iv4*>(Qb + LQKV(frow, lq * 16));
      fv4 s = fv4{0.f, 0.f, 0.f, 0.f};
      mfma32(s, kf, qf);                 // swapped QK^T
      float mx = fmaxf(fmaxf(s[0], s[1]), fmaxf(s[2], s[3]));
      mx = fmaxf(mx, __shfl_xor(mx, 16));
      mx = fmaxf(mx, __shfl_xor(mx, 32));
      const float Cc = 0.25503373f;      // log2(e)/sqrt(32)
      float e0 = exp2f((s[0] - mx) * Cc), e1 = exp2f((s[1] - mx) * Cc);
      float e2 = exp2f((s[2] - mx) * Cc), e3 = exp2f((s[3] - mx) * Cc);
      float sum = e0 + e1 + e2 + e3;
      sum += __shfl_xor(sum, 16);
      sum += __shfl_xor(sum, 32);
      float inv = 1.0f / sum;
      iv2 pa; pa[0] = (int)pk2(bf16rne(e0 * inv), bf16rne(e1 * inv));
              pa[1] = (int)pk2(bf16rne(e2 * inv), bf16rne(e3 * inv));
      const int r0 = w * 16 + lq * 4;
      #pragma unroll
      for (int dvt = 0; dvt < 2; ++dvt) {
        int cb = (dvt * 16 + lane15) * 2;
        uint32_t v0 = *reinterpret_cast<const uint16_t*>(Vb + LQKV(r0 + 0, cb));
        uint32_t v1 = *reinterpret_cast<const uint16_t*>(Vb + LQKV(r0 + 1, cb));
        uint32_t v2 = *reinterpret_cast<const uint16_t*>(Vb + LQKV(r0 + 2, cb));
        uint32_t v3 = *reinterpret_cast<const uint16_t*>(Vb + LQKV(r0 + 3, cb));
        iv2 bv; bv[0] = (int)pk2(v0, v1); bv[1] = (int)pk2(v2, v3);
        fv4 cacc = fv4{0.f, 0.f, 0.f, 0.f};
        mfma16(cacc, pa, bv);
        #pragma unroll
        for (int r = 0; r < 4; ++r)
          *reinterpret_cast<uint16_t*>(Cb + LQKV(r0 + r, cb)) =
              (uint16_t)bf16rne(cacc[r]);
      }
    }

    // slot 3: W0 tile in bufB (LGKM0 also publishes attn's Cb writes)
    if (hc < 7) { VMWAIT2; } else { VMWAIT0; }
    LGKM0; BAR();
    #pragma unroll
    for (int mt = 0; mt < 2; ++mt) {
      int ar = mq2 * 32 + mt * 16 + lane15;
      iv4 af = *reinterpret_cast<const iv4*>(Cb + LQKV(ar, lq * 16));
      #pragma unroll
      for (int nt = 0; nt < 8; ++nt) {
        int n = nh * 128 + nt * 16 + lane15;
        iv4 bfg = *reinterpret_cast<const iv4*>(
            bufB + (n >> 1) * 128 + ((((n & 1) << 6) + lq * 16) ^ (((n >> 1) & 7) << 4)));
        mfma32(outacc[mt][nt], af, bfg);
      }
    }
    BAR();
    if (hc < 7) stage_qkv(WkT, c0 + 32, bufB, w, l);   // issue Wk(hc+1)
    #undef COMPUTE_QKV
  } // hc

  // ---- scatter out (fp32, 64B segments per 16-lane group) ----
  #pragma unroll
  for (int mt = 0; mt < 2; ++mt) {
    int rb = mq2 * 32 + mt * 16 + lq * 4;
    int t0 = s2t[slot0 + rb + 0];
    int t1 = s2t[slot0 + rb + 1];
    int t2 = s2t[slot0 + rb + 2];
    int t3 = s2t[slot0 + rb + 3];
    #pragma unroll
    for (int nt = 0; nt < 8; ++nt) {
      int col = nh * 128 + nt * 16 + lane15;
      if (t0 >= 0) out[(size_t)t0 * E_ + col] = outacc[mt][nt][0];
      if (t1 >= 0) out[(size_t)t1 * E_ + col] = outacc[mt][nt][1];
      if (t2 >= 0) out[(size_t)t2 * E_ + col] = outacc[mt][nt][2];
      if (t3 >= 0) out[(size_t)t3 * E_ + col] = outacc[mt][nt][3];
    }
  }
}

extern "C" void kernel_launch(void* const* d_in, const int* in_sizes, int n_in,
                              void* d_out, int out_size, void* d_ws, size_t ws_size,
                              hipStream_t stream) {
  (void)in_sizes; (void)n_in; (void)out_size; (void)ws_size;
  const float* emb = (const float*)d_in[0];
  const float* Wq  = (const float*)d_in[1];
  const float* Wk  = (const float*)d_in[2];
  const float* Wv  = (const float*)d_in[3];
  const float* W0  = (const float*)d_in[4];
  const int*   pos = (const int*)d_in[5];
  float* out = (float*)d_out;

  // ws layout: cnt 32KB | s2t 512KB | WT(4x bf16 256x256) 512KB
  int* cnt = (int*)d_ws;
  int* s2t = (int*)((char*)d_ws + 32768);
  uint16_t* WT = (uint16_t*)((char*)d_ws + 32768 + 524288);

  (void)hipFuncSetAttribute(reinterpret_cast<const void*>(k_main),
                            hipFuncAttributeMaxDynamicSharedMemorySize, 65536);

  k_init <<<512, 256, 0, stream>>>(cnt, s2t);
  k_trans<<<dim3(256, 4), 256, 0, stream>>>(Wq, Wk, Wv, W0, WT);
  k_rank <<<512, 256, 0, stream>>>(pos, cnt, s2t);
  k_main <<<NWG, 512, 65536, stream>>>(emb, s2t, WT, out);
}

// Round 7
// 177.375 us; speedup vs baseline: 2.7553x; 1.0079x over previous
//
#include <hip/hip_runtime.h>
#include <stdint.h>

// Problem constants (fixed instance)
#define B_    32
#define S_    4096
#define E_    256
#define P_    256
#define M_    16
#define G_    (B_*P_)      // 8192 groups
#define NSLOT (G_*M_)      // 131072 slots (== tokens)
#define GPW   8            // groups per workgroup
#define ROWS  128          // 8 groups * 16 slots
#define NWG   (G_/GPW)     // 1024 workgroups

typedef float fv4 __attribute__((ext_vector_type(4)));
typedef int   iv4 __attribute__((ext_vector_type(4)));
typedef int   iv2 __attribute__((ext_vector_type(2)));
typedef __bf16 bv8 __attribute__((ext_vector_type(8)));
typedef short  sv4 __attribute__((ext_vector_type(4)));

__device__ __forceinline__ uint32_t bf16rne(float f) {
  uint32_t u = __builtin_bit_cast(uint32_t, f);
  u += 0x7fffu + ((u >> 16) & 1u);
  return u >> 16;
}
__device__ __forceinline__ uint32_t pk2(uint32_t lo, uint32_t hi) {
  return (lo & 0xffffu) | (hi << 16);
}
// Builtins (NOT inline asm): hazard recognizer must see MFMAs (round-1 NaN).
__device__ __forceinline__ void mfma32(fv4& d, iv4 a, iv4 b) {
  d = __builtin_amdgcn_mfma_f32_16x16x32_bf16(
        __builtin_bit_cast(bv8, a), __builtin_bit_cast(bv8, b), d, 0, 0, 0);
}
__device__ __forceinline__ void mfma16(fv4& d, iv2 a, iv2 b) {
  d = __builtin_amdgcn_mfma_f32_16x16x16bf16_1k(
        __builtin_bit_cast(sv4, a), __builtin_bit_cast(sv4, b), d, 0, 0, 0);
}
// async global->LDS, 16B/lane; LDS dest = wave-uniform base + lane*16.
__device__ __forceinline__ void gload_lds16(const void* g, void* l) {
  __builtin_amdgcn_global_load_lds(
      (const __attribute__((address_space(1))) uint32_t*)g,
      (__attribute__((address_space(3))) uint32_t*)l, 16, 0, 0);
}

// XOR swizzle for 512B rows: flips byte bits 4-6 by row&7 (involution).
#define SWZ(off, row) ((off) ^ (((row) & 7) << 4))
// 64B-row buffers stored as [pair][128B], swizzled by pair&7 (bits 4-6).
#define LQKV(row, cb) ( ((row) >> 1) * 128 + \
    (((((row) & 1) << 6) + (cb)) ^ ((((row) >> 1) & 7) << 4)) )

// Raw barrier + counted waits (T3/T4): loads stay in flight across barriers.
#define BAR()   { asm volatile("" ::: "memory"); __builtin_amdgcn_s_barrier(); \
                  asm volatile("" ::: "memory"); }
#define VMWAIT1 asm volatile("s_waitcnt vmcnt(1)" ::: "memory")
#define VMWAIT0 asm volatile("s_waitcnt vmcnt(0)" ::: "memory")
#define LGKM0   asm volatile("s_waitcnt lgkmcnt(0)" ::: "memory")

// ---------------- prep kernels ----------------
__global__ void k_init(int* cnt, int* s2t) {
  int i = blockIdx.x * 256 + threadIdx.x;
  if (i < G_) cnt[i] = 0;
  if (i < NSLOT) s2t[i] = -1;
}

__global__ void k_trans(const float* __restrict__ Wq, const float* __restrict__ Wk,
                        const float* __restrict__ Wv, const float* __restrict__ W0,
                        uint16_t* __restrict__ WT) {
  // WT: 4 concatenated [256][256] bf16, WT[w][n][k] = bf16(W[w][k][n])
  int o = blockIdx.x * 256 + threadIdx.x;     // 0..65535
  int wsel = blockIdx.y;
  const float* W = (wsel == 0) ? Wq : (wsel == 1) ? Wk : (wsel == 2) ? Wv : W0;
  int n = o >> 8, k = o & 255;
  WT[(size_t)wsel * 65536 + o] = (uint16_t)bf16rne(W[k * 256 + n]);
}

__global__ void k_rank(const int* __restrict__ pos, int* cnt, int* s2t) {
  int i = blockIdx.x * 256 + threadIdx.x;
  if (i >= B_ * S_) return;
  int p = pos[i];
  if (p < 0 || p >= P_) return;          // invalid -> dropped (stays -1)
  int b = i >> 12;                       // i / S_
  int g = (b << 8) + p;
  int r = atomicAdd(&cnt[g], 1);         // arbitrary slot order: attention is
  if (r < M_) s2t[g * M_ + r] = i;       // permutation-equivariant, so OK
}

// stage one QKV weight tile (16 KiB): 1 gload instr per wave (1 KiB).
__device__ __forceinline__ void stage_qkv(const uint16_t* Wt, int c0, char* buf,
                                          int w, int l) {
  int n = w * 2 + (l >> 5);              // local n-row 0..31
  int seg = l & 31;
  gload_lds16(reinterpret_cast<const char*>(Wt) + (size_t)(c0 + n) * 512 + SWZ(seg * 16, n),
              buf + w * 1024);
}
// stage W0 k-slice tile: [256 n][64B], stored [128 pair][128B] pair-swizzled.
__device__ __forceinline__ void stage_w0(const uint16_t* W0T, int c0, char* buf,
                                         int w, int l) {
  int pair = w * 8 + (l >> 3);           // 0..127
  int jp = ((l & 7) * 16) ^ ((pair & 7) << 4);
  int n = 2 * pair + (jp >> 6);
  gload_lds16(reinterpret_cast<const char*>(W0T) + (size_t)n * 512 + c0 * 2 + (jp & 63),
              buf + w * 1024);
}

// ---------------- fused main kernel ----------------
// 1 WG = 8 groups = 128 rows, 1024 threads = 16 waves (4 waves/SIMD at
// <=128 unified regs/wave; r6's 8-wave version hit ~180 regs -> 2/SIMD).
// Wave = (rb = w>>1: 16-row block, ch = w&1: col half).
// Chunk = 32 cols (1 head); tile stream Wq,Wk,Wv,W0 per chunk, 2-deep
// ping-pong (bufA/bufB), counted vmcnt so loads span barriers.
// Ledger (1 vmem instr/wave/tile): at each consumer slot own outstanding
// = 2 (tiles t, t+1); VMWAIT1 completes tile t; VMWAIT0 only at hc=7.
__global__ __launch_bounds__(1024, 1) void k_main(
    const float* __restrict__ emb, const int* __restrict__ s2t,
    const uint16_t* __restrict__ WT, float* __restrict__ out) {
  extern __shared__ char smem[];
  char* bufA = smem;            // 16 KiB
  char* bufB = smem + 16384;    // 16 KiB
  char* Qb = smem + 32768;      // 8 KiB [128 rows][32 cols] bf16, pair-swizzled
  char* Kb = smem + 40960;
  char* Vb = smem + 49152;
  char* Cb = smem + 57344;

  const uint16_t* WqT = WT;
  const uint16_t* WkT = WT + 65536;
  const uint16_t* WvT = WT + 131072;
  const uint16_t* W0T = WT + 196608;

  const int tid = threadIdx.x;
  const int l = tid & 63;
  const int w = tid >> 6;           // wave 0..15
  const int lane15 = l & 15;
  const int lq = l >> 4;            // lane quad 0..3
  const int rb = w >> 1;            // 16-row block 0..7
  const int ch = w & 1;             // col half
  const int slot0 = blockIdx.x * ROWS;

  // ---- gather: 128 token rows -> bf16 X overlay on all 64 KiB ----
  #pragma unroll 2
  for (int rl = 0; rl < 8; ++rl) {
    int row = w * 8 + rl;
    int t = s2t[slot0 + row];            // wave-uniform (scalar load)
    uint32_t u0 = 0, u1 = 0;
    if (t >= 0) {
      const float4 v = *reinterpret_cast<const float4*>(emb + (size_t)t * E_ + (l << 2));
      u0 = pk2(bf16rne(v.x), bf16rne(v.y));
      u1 = pk2(bf16rne(v.z), bf16rne(v.w));
    }
    iv2 val; val[0] = (int)u0; val[1] = (int)u1;
    *reinterpret_cast<iv2*>(smem + row * 512 + SWZ(l * 8, row)) = val;
  }
  __syncthreads();

  // ---- X A-fragments: rows rb*16..+16, full K (32 VGPR) ----
  iv4 xf[8];
  const int arow = rb * 16 + lane15;
  #pragma unroll
  for (int ks = 0; ks < 8; ++ks)
    xf[ks] = *reinterpret_cast<const iv4*>(smem + arow * 512 + SWZ(ks * 64 + lq * 16, arow));
  __syncthreads();   // all xf read; overlay region now reusable

  fv4 outacc[8];     // 16 rows x 128 cols per wave, persists across chunks
  #pragma unroll
  for (int i = 0; i < 8; ++i) outacc[i] = fv4{0.f, 0.f, 0.f, 0.f};

  // prologue: 2 tiles in flight
  stage_qkv(WqT, 0, bufA, w, l);
  stage_qkv(WkT, 0, bufB, w, l);

  for (int hc = 0; hc < 8; ++hc) {       // 8 chunks of 32 cols (1 head)
    const int c0 = hc * 32;

    // QKV projection: wave computes 16 rows x 16 cols from tile in `buf`
    #define COMPUTE_QKV(buf, dst)                                            \
    {                                                                        \
      fv4 a0 = fv4{0.f,0.f,0.f,0.f};                                         \
      const int n0 = ch * 16 + lane15;                                       \
      _Pragma("unroll")                                                      \
      for (int ks = 0; ks < 8; ++ks) {                                       \
        iv4 b0 = *reinterpret_cast<const iv4*>((buf) + n0 * 512 + SWZ(ks * 64 + lq * 16, n0)); \
        mfma32(a0, xf[ks], b0);                                              \
      }                                                                      \
      _Pragma("unroll")                                                      \
      for (int r = 0; r < 4; ++r) {                                          \
        int row = rb * 16 + lq * 4 + r;                                      \
        *reinterpret_cast<uint16_t*>((dst) + LQKV(row, n0 * 2)) =            \
            (uint16_t)bf16rne(a0[r]);                                        \
      }                                                                      \
    }

    // slot 0: Wq tile in bufA
    VMWAIT1; BAR();
    COMPUTE_QKV(bufA, Qb);
    LGKM0; BAR();
    stage_qkv(WvT, c0, bufA, w, l);      // issue Wv(hc)

    // slot 1: Wk tile in bufB
    VMWAIT1; BAR();
    COMPUTE_QKV(bufB, Kb);
    LGKM0; BAR();
    stage_w0(W0T, c0, bufB, w, l);       // issue W0(hc)

    // slot 2: Wv tile in bufA
    VMWAIT1; BAR();
    COMPUTE_QKV(bufA, Vb);
    LGKM0; BAR();
    if (hc < 7) stage_qkv(WqT, c0 + 32, bufA, w, l);   // issue Wq(hc+1)

    // ---- attention: group g = rb, head = hc; V-half dvt = ch ----
    {
      const int frow = rb * 16 + lane15;
      iv4 kf = *reinterpret_cast<const iv4*>(Kb + LQKV(frow, lq * 16));
      iv4 qf = *reinterpret_cast<const iv4*>(Qb + LQKV(frow, lq * 16));
      fv4 s = fv4{0.f, 0.f, 0.f, 0.f};
      mfma32(s, kf, qf);                 // swapped QK^T (pair-redundant, cheap)
      float mx = fmaxf(fmaxf(s[0], s[1]), fmaxf(s[2], s[3]));
      mx = fmaxf(mx, __shfl_xor(mx, 16));
      mx = fmaxf(mx, __shfl_xor(mx, 32));
      const float Cc = 0.25503373f;      // log2(e)/sqrt(32)
      float e0 = exp2f((s[0] - mx) * Cc), e1 = exp2f((s[1] - mx) * Cc);
      float e2 = exp2f((s[2] - mx) * Cc), e3 = exp2f((s[3] - mx) * Cc);
      float sum = e0 + e1 + e2 + e3;
      sum += __shfl_xor(sum, 16);
      sum += __shfl_xor(sum, 32);
      float inv = 1.0f / sum;
      iv2 pa; pa[0] = (int)pk2(bf16rne(e0 * inv), bf16rne(e1 * inv));
              pa[1] = (int)pk2(bf16rne(e2 * inv), bf16rne(e3 * inv));
      const int r0 = rb * 16 + lq * 4;
      const int cb = (ch * 16 + lane15) * 2;
      uint32_t v0 = *reinterpret_cast<const uint16_t*>(Vb + LQKV(r0 + 0, cb));
      uint32_t v1 = *reinterpret_cast<const uint16_t*>(Vb + LQKV(r0 + 1, cb));
      uint32_t v2 = *reinterpret_cast<const uint16_t*>(Vb + LQKV(r0 + 2, cb));
      uint32_t v3 = *reinterpret_cast<const uint16_t*>(Vb + LQKV(r0 + 3, cb));
      iv2 bv; bv[0] = (int)pk2(v0, v1); bv[1] = (int)pk2(v2, v3);
      fv4 cacc = fv4{0.f, 0.f, 0.f, 0.f};
      mfma16(cacc, pa, bv);
      #pragma unroll
      for (int r = 0; r < 4; ++r)
        *reinterpret_cast<uint16_t*>(Cb + LQKV(r0 + r, cb)) =
            (uint16_t)bf16rne(cacc[r]);
    }

    // slot 3: W0 tile in bufB (LGKM0 also publishes attn's Cb writes)
    if (hc < 7) { VMWAIT1; } else { VMWAIT0; }
    LGKM0; BAR();
    {
      int ar = rb * 16 + lane15;
      iv4 af = *reinterpret_cast<const iv4*>(Cb + LQKV(ar, lq * 16));
      #pragma unroll
      for (int nt = 0; nt < 8; ++nt) {
        int n = ch * 128 + nt * 16 + lane15;
        iv4 bfg = *reinterpret_cast<const iv4*>(
            bufB + (n >> 1) * 128 + ((((n & 1) << 6) + lq * 16) ^ (((n >> 1) & 7) << 4)));
        mfma32(outacc[nt], af, bfg);
      }
    }
    BAR();
    if (hc < 7) stage_qkv(WkT, c0 + 32, bufB, w, l);   // issue Wk(hc+1)
    #undef COMPUTE_QKV
  } // hc

  // ---- scatter out (fp32, 64B segments per 16-lane group) ----
  #pragma unroll
  for (int r = 0; r < 4; ++r) {
    int t = s2t[slot0 + rb * 16 + lq * 4 + r];
    if (t < 0) continue;
    #pragma unroll
    for (int nt = 0; nt < 8; ++nt) {
      int col = ch * 128 + nt * 16 + lane15;
      out[(size_t)t * E_ + col] = outacc[nt][r];
    }
  }
}

extern "C" void kernel_launch(void* const* d_in, const int* in_sizes, int n_in,
                              void* d_out, int out_size, void* d_ws, size_t ws_size,
                              hipStream_t stream) {
  (void)in_sizes; (void)n_in; (void)out_size; (void)ws_size;
  const float* emb = (const float*)d_in[0];
  const float* Wq  = (const float*)d_in[1];
  const float* Wk  = (const float*)d_in[2];
  const float* Wv  = (const float*)d_in[3];
  const float* W0  = (const float*)d_in[4];
  const int*   pos = (const int*)d_in[5];
  float* out = (float*)d_out;

  // ws layout: cnt 32KB | s2t 512KB | WT(4x bf16 256x256) 512KB
  int* cnt = (int*)d_ws;
  int* s2t = (int*)((char*)d_ws + 32768);
  uint16_t* WT = (uint16_t*)((char*)d_ws + 32768 + 524288);

  (void)hipFuncSetAttribute(reinterpret_cast<const void*>(k_main),
                            hipFuncAttributeMaxDynamicSharedMemorySize, 65536);

  k_init <<<512, 256, 0, stream>>>(cnt, s2t);
  k_trans<<<dim3(256, 4), 256, 0, stream>>>(Wq, Wk, Wv, W0, WT);
  k_rank <<<512, 256, 0, stream>>>(pos, cnt, s2t);
  k_main <<<NWG, 1024, 65536, stream>>>(emb, s2t, WT, out);
}

// Round 8
// 177.186 us; speedup vs baseline: 2.7582x; 1.0011x over previous
//
#include <hip/hip_runtime.h>
#include <stdint.h>

// Problem constants (fixed instance)
#define B_    32
#define S_    4096
#define E_    256
#define P_    256
#define M_    16
#define G_    (B_*P_)      // 8192 groups
#define NSLOT (G_*M_)      // 131072 slots (== tokens)
#define GPW   8            // groups per workgroup
#define ROWS  128          // 8 groups * 16 slots
#define NWG   (G_/GPW)     // 1024 workgroups

typedef float fv4 __attribute__((ext_vector_type(4)));
typedef int   iv4 __attribute__((ext_vector_type(4)));
typedef int   iv2 __attribute__((ext_vector_type(2)));
typedef __bf16 bv8 __attribute__((ext_vector_type(8)));
typedef short  sv4 __attribute__((ext_vector_type(4)));

__device__ __forceinline__ uint32_t bf16rne(float f) {
  uint32_t u = __builtin_bit_cast(uint32_t, f);
  u += 0x7fffu + ((u >> 16) & 1u);
  return u >> 16;
}
__device__ __forceinline__ uint32_t pk2(uint32_t lo, uint32_t hi) {
  return (lo & 0xffffu) | (hi << 16);
}
// Builtins (NOT inline asm): hazard recognizer must see MFMAs (round-1 NaN).
__device__ __forceinline__ void mfma32(fv4& d, iv4 a, iv4 b) {
  d = __builtin_amdgcn_mfma_f32_16x16x32_bf16(
        __builtin_bit_cast(bv8, a), __builtin_bit_cast(bv8, b), d, 0, 0, 0);
}
__device__ __forceinline__ void mfma16(fv4& d, iv2 a, iv2 b) {
  d = __builtin_amdgcn_mfma_f32_16x16x16bf16_1k(
        __builtin_bit_cast(sv4, a), __builtin_bit_cast(sv4, b), d, 0, 0, 0);
}
// async global->LDS, 16B/lane; LDS dest = wave-uniform base + lane*16.
__device__ __forceinline__ void gload_lds16(const void* g, void* l) {
  __builtin_amdgcn_global_load_lds(
      (const __attribute__((address_space(1))) uint32_t*)g,
      (__attribute__((address_space(3))) uint32_t*)l, 16, 0, 0);
}

// XOR swizzle for 512B rows: flips byte bits 4-6 by row&7 (involution).
#define SWZ(off, row) ((off) ^ (((row) & 7) << 4))
// 64B-row buffers stored as [pair][128B], swizzled by pair&7 (bits 4-6).
#define LQKV(row, cb) ( ((row) >> 1) * 128 + \
    (((((row) & 1) << 6) + (cb)) ^ ((((row) >> 1) & 7) << 4)) )

// Raw barrier + counted waits (T3/T4): loads stay in flight across barriers.
#define BAR()   { asm volatile("" ::: "memory"); __builtin_amdgcn_s_barrier(); \
                  asm volatile("" ::: "memory"); }
#define VMWAIT1 asm volatile("s_waitcnt vmcnt(1)" ::: "memory")
#define VMWAIT0 asm volatile("s_waitcnt vmcnt(0)" ::: "memory")
#define LGKM0   asm volatile("s_waitcnt lgkmcnt(0)" ::: "memory")

// ---------------- prep kernels ----------------
__global__ void k_init(int* cnt, int* s2t) {
  int i = blockIdx.x * 256 + threadIdx.x;
  if (i < G_) cnt[i] = 0;
  if (i < NSLOT) s2t[i] = -1;
}

__global__ void k_trans(const float* __restrict__ Wq, const float* __restrict__ Wk,
                        const float* __restrict__ Wv, const float* __restrict__ W0,
                        uint16_t* __restrict__ WT) {
  // WT: 4 concatenated [256][256] bf16, WT[w][n][k] = bf16(W[w][k][n])
  int o = blockIdx.x * 256 + threadIdx.x;     // 0..65535
  int wsel = blockIdx.y;
  const float* W = (wsel == 0) ? Wq : (wsel == 1) ? Wk : (wsel == 2) ? Wv : W0;
  int n = o >> 8, k = o & 255;
  WT[(size_t)wsel * 65536 + o] = (uint16_t)bf16rne(W[k * 256 + n]);
}

__global__ void k_rank(const int* __restrict__ pos, int* cnt, int* s2t) {
  int i = blockIdx.x * 256 + threadIdx.x;
  if (i >= B_ * S_) return;
  int p = pos[i];
  if (p < 0 || p >= P_) return;          // invalid -> dropped (stays -1)
  int b = i >> 12;                       // i / S_
  int g = (b << 8) + p;
  int r = atomicAdd(&cnt[g], 1);         // arbitrary slot order: attention is
  if (r < M_) s2t[g * M_ + r] = i;       // permutation-equivariant, so OK
}

// stage one QKV weight tile (16 KiB): 1 gload instr per wave (1 KiB).
__device__ __forceinline__ void stage_qkv(const uint16_t* Wt, int c0, char* buf,
                                          int w, int l) {
  int n = w * 2 + (l >> 5);              // local n-row 0..31
  int seg = l & 31;
  gload_lds16(reinterpret_cast<const char*>(Wt) + (size_t)(c0 + n) * 512 + SWZ(seg * 16, n),
              buf + w * 1024);
}
// stage W0 k-slice tile: [256 n][64B], stored [128 pair][128B] pair-swizzled.
__device__ __forceinline__ void stage_w0(const uint16_t* W0T, int c0, char* buf,
                                         int w, int l) {
  int pair = w * 8 + (l >> 3);           // 0..127
  int jp = ((l & 7) * 16) ^ ((pair & 7) << 4);
  int n = 2 * pair + (jp >> 6);
  gload_lds16(reinterpret_cast<const char*>(W0T) + (size_t)n * 512 + c0 * 2 + (jp & 63),
              buf + w * 1024);
}

// ---------------- fused main kernel ----------------
// 1 WG = 8 groups = 128 rows, 1024 threads = 16 waves.
// Register policy: amdgpu_waves_per_eu(4,4) pins the allocator to exactly
// 4 waves/SIMD = 128 unified VGPRs/wave. (__launch_bounds__ 2nd-arg variants
// {(256,1),(512,2),(512,4),(1024,4),(1024,1)} gave {256,84/116,64,64,64} —
// the 1024-thread cases forced a 64-reg target and spilled ~30MB/launch.)
// Wave = (rb = w>>1: 16-row block, ch = w&1: col half).
// Chunk = 32 cols (1 head); tile stream Wq,Wk,Wv,W0 per chunk, 2-deep
// ping-pong (bufA/bufB), counted vmcnt so loads span barriers.
// Ledger (1 vmem instr/wave/tile): at each consumer slot own outstanding
// = 2 (tiles t, t+1); VMWAIT1 completes tile t; VMWAIT0 only at hc=7.
__global__ __launch_bounds__(1024)
__attribute__((amdgpu_waves_per_eu(4, 4))) void k_main(
    const float* __restrict__ emb, const int* __restrict__ s2t,
    const uint16_t* __restrict__ WT, float* __restrict__ out) {
  extern __shared__ char smem[];
  char* bufA = smem;            // 16 KiB
  char* bufB = smem + 16384;    // 16 KiB
  char* Qb = smem + 32768;      // 8 KiB [128 rows][32 cols] bf16, pair-swizzled
  char* Kb = smem + 40960;
  char* Vb = smem + 49152;
  char* Cb = smem + 57344;

  const uint16_t* WqT = WT;
  const uint16_t* WkT = WT + 65536;
  const uint16_t* WvT = WT + 131072;
  const uint16_t* W0T = WT + 196608;

  const int tid = threadIdx.x;
  const int l = tid & 63;
  const int w = tid >> 6;           // wave 0..15
  const int lane15 = l & 15;
  const int lq = l >> 4;            // lane quad 0..3
  const int rb = w >> 1;            // 16-row block 0..7
  const int ch = w & 1;             // col half
  const int slot0 = blockIdx.x * ROWS;

  // ---- gather: 128 token rows -> bf16 X overlay on all 64 KiB ----
  #pragma unroll 2
  for (int rl = 0; rl < 8; ++rl) {
    int row = w * 8 + rl;
    int t = s2t[slot0 + row];            // wave-uniform (scalar load)
    uint32_t u0 = 0, u1 = 0;
    if (t >= 0) {
      const float4 v = *reinterpret_cast<const float4*>(emb + (size_t)t * E_ + (l << 2));
      u0 = pk2(bf16rne(v.x), bf16rne(v.y));
      u1 = pk2(bf16rne(v.z), bf16rne(v.w));
    }
    iv2 val; val[0] = (int)u0; val[1] = (int)u1;
    *reinterpret_cast<iv2*>(smem + row * 512 + SWZ(l * 8, row)) = val;
  }
  __syncthreads();

  // ---- X A-fragments: rows rb*16..+16, full K (32 VGPR) ----
  iv4 xf[8];
  const int arow = rb * 16 + lane15;
  #pragma unroll
  for (int ks = 0; ks < 8; ++ks)
    xf[ks] = *reinterpret_cast<const iv4*>(smem + arow * 512 + SWZ(ks * 64 + lq * 16, arow));
  __syncthreads();   // all xf read; overlay region now reusable

  fv4 outacc[8];     // 16 rows x 128 cols per wave, persists across chunks
  #pragma unroll
  for (int i = 0; i < 8; ++i) outacc[i] = fv4{0.f, 0.f, 0.f, 0.f};

  // prologue: 2 tiles in flight
  stage_qkv(WqT, 0, bufA, w, l);
  stage_qkv(WkT, 0, bufB, w, l);

  for (int hc = 0; hc < 8; ++hc) {       // 8 chunks of 32 cols (1 head)
    const int c0 = hc * 32;

    // QKV projection: wave computes 16 rows x 16 cols from tile in `buf`
    #define COMPUTE_QKV(buf, dst)                                            \
    {                                                                        \
      fv4 a0 = fv4{0.f,0.f,0.f,0.f};                                         \
      const int n0 = ch * 16 + lane15;                                       \
      _Pragma("unroll")                                                      \
      for (int ks = 0; ks < 8; ++ks) {                                       \
        iv4 b0 = *reinterpret_cast<const iv4*>((buf) + n0 * 512 + SWZ(ks * 64 + lq * 16, n0)); \
        mfma32(a0, xf[ks], b0);                                              \
      }                                                                      \
      _Pragma("unroll")                                                      \
      for (int r = 0; r < 4; ++r) {                                          \
        int row = rb * 16 + lq * 4 + r;                                      \
        *reinterpret_cast<uint16_t*>((dst) + LQKV(row, n0 * 2)) =            \
            (uint16_t)bf16rne(a0[r]);                                        \
      }                                                                      \
    }

    // slot 0: Wq tile in bufA
    VMWAIT1; BAR();
    COMPUTE_QKV(bufA, Qb);
    LGKM0; BAR();
    stage_qkv(WvT, c0, bufA, w, l);      // issue Wv(hc)

    // slot 1: Wk tile in bufB
    VMWAIT1; BAR();
    COMPUTE_QKV(bufB, Kb);
    LGKM0; BAR();
    stage_w0(W0T, c0, bufB, w, l);       // issue W0(hc)

    // slot 2: Wv tile in bufA
    VMWAIT1; BAR();
    COMPUTE_QKV(bufA, Vb);
    LGKM0; BAR();
    if (hc < 7) stage_qkv(WqT, c0 + 32, bufA, w, l);   // issue Wq(hc+1)

    // ---- attention: group g = rb, head = hc; V-half dvt = ch ----
    {
      const int frow = rb * 16 + lane15;
      iv4 kf = *reinterpret_cast<const iv4*>(Kb + LQKV(frow, lq * 16));
      iv4 qf = *reinterpret_cast<const iv4*>(Qb + LQKV(frow, lq * 16));
      fv4 s = fv4{0.f, 0.f, 0.f, 0.f};
      mfma32(s, kf, qf);                 // swapped QK^T (pair-redundant, cheap)
      float mx = fmaxf(fmaxf(s[0], s[1]), fmaxf(s[2], s[3]));
      mx = fmaxf(mx, __shfl_xor(mx, 16));
      mx = fmaxf(mx, __shfl_xor(mx, 32));
      const float Cc = 0.25503373f;      // log2(e)/sqrt(32)
      float e0 = exp2f((s[0] - mx) * Cc), e1 = exp2f((s[1] - mx) * Cc);
      float e2 = exp2f((s[2] - mx) * Cc), e3 = exp2f((s[3] - mx) * Cc);
      float sum = e0 + e1 + e2 + e3;
      sum += __shfl_xor(sum, 16);
      sum += __shfl_xor(sum, 32);
      float inv = 1.0f / sum;
      iv2 pa; pa[0] = (int)pk2(bf16rne(e0 * inv), bf16rne(e1 * inv));
              pa[1] = (int)pk2(bf16rne(e2 * inv), bf16rne(e3 * inv));
      const int r0 = rb * 16 + lq * 4;
      const int cb = (ch * 16 + lane15) * 2;
      uint32_t v0 = *reinterpret_cast<const uint16_t*>(Vb + LQKV(r0 + 0, cb));
      uint32_t v1 = *reinterpret_cast<const uint16_t*>(Vb + LQKV(r0 + 1, cb));
      uint32_t v2 = *reinterpret_cast<const uint16_t*>(Vb + LQKV(r0 + 2, cb));
      uint32_t v3 = *reinterpret_cast<const uint16_t*>(Vb + LQKV(r0 + 3, cb));
      iv2 bv; bv[0] = (int)pk2(v0, v1); bv[1] = (int)pk2(v2, v3);
      fv4 cacc = fv4{0.f, 0.f, 0.f, 0.f};
      mfma16(cacc, pa, bv);
      #pragma unroll
      for (int r = 0; r < 4; ++r)
        *reinterpret_cast<uint16_t*>(Cb + LQKV(r0 + r, cb)) =
            (uint16_t)bf16rne(cacc[r]);
    }

    // slot 3: W0 tile in bufB (LGKM0 also publishes attn's Cb writes)
    if (hc < 7) { VMWAIT1; } else { VMWAIT0; }
    LGKM0; BAR();
    {
      int ar = rb * 16 + lane15;
      iv4 af = *reinterpret_cast<const iv4*>(Cb + LQKV(ar, lq * 16));
      #pragma unroll
      for (int nt = 0; nt < 8; ++nt) {
        int n = ch * 128 + nt * 16 + lane15;
        iv4 bfg = *reinterpret_cast<const iv4*>(
            bufB + (n >> 1) * 128 + ((((n & 1) << 6) + lq * 16) ^ (((n >> 1) & 7) << 4)));
        mfma32(outacc[nt], af, bfg);
      }
    }
    BAR();
    if (hc < 7) stage_qkv(WkT, c0 + 32, bufB, w, l);   // issue Wk(hc+1)
    #undef COMPUTE_QKV
  } // hc

  // ---- scatter out (fp32, 64B segments per 16-lane group) ----
  #pragma unroll
  for (int r = 0; r < 4; ++r) {
    int t = s2t[slot0 + rb * 16 + lq * 4 + r];
    if (t < 0) continue;
    #pragma unroll
    for (int nt = 0; nt < 8; ++nt) {
      int col = ch * 128 + nt * 16 + lane15;
      out[(size_t)t * E_ + col] = outacc[nt][r];
    }
  }
}

extern "C" void kernel_launch(void* const* d_in, const int* in_sizes, int n_in,
                              void* d_out, int out_size, void* d_ws, size_t ws_size,
                              hipStream_t stream) {
  (void)in_sizes; (void)n_in; (void)out_size; (void)ws_size;
  const float* emb = (const float*)d_in[0];
  const float* Wq  = (const float*)d_in[1];
  const float* Wk  = (const float*)d_in[2];
  const float* Wv  = (const float*)d_in[3];
  const float* W0  = (const float*)d_in[4];
  const int*   pos = (const int*)d_in[5];
  float* out = (float*)d_out;

  // ws layout: cnt 32KB | s2t 512KB | WT(4x bf16 256x256) 512KB
  int* cnt = (int*)d_ws;
  int* s2t = (int*)((char*)d_ws + 32768);
  uint16_t* WT = (uint16_t*)((char*)d_ws + 32768 + 524288);

  (void)hipFuncSetAttribute(reinterpret_cast<const void*>(k_main),
                            hipFuncAttributeMaxDynamicSharedMemorySize, 65536);

  k_init <<<512, 256, 0, stream>>>(cnt, s2t);
  k_trans<<<dim3(256, 4), 256, 0, stream>>>(Wq, Wk, Wv, W0, WT);
  k_rank <<<512, 256, 0, stream>>>(pos, cnt, s2t);
  k_main <<<NWG, 1024, 65536, stream>>>(emb, s2t, WT, out);
}